// Round 4
// baseline (282.107 us; speedup 1.0000x reference)
//
#include <hip/hip_runtime.h>

#define NEG_INF_F (-9000000000000000.0f)
// B=256, N=32, IN=128, OUT=64, ED=32, H=4
// ws layout (floats):
//   [0..512)      v_src[h][i]
//   [512..1024)   v_dst[h][i]
//   [1024..1152)  v_edge[h][e]
//   [1152..33920) ss[bb][h][n]   (256*4*32)
//   [40960..)     agg[bid][h][i] (8192*4*128 = 4,194,304 floats)

// ---------------- K0: projection vectors v_src/v_dst/v_edge ----------------
__global__ __launch_bounds__(256) void k_vecs(const float* __restrict__ Wsrc,
                                              const float* __restrict__ Wdst,
                                              const float* __restrict__ Wedge,
                                              const float* __restrict__ attns,
                                              float* __restrict__ ws) {
    int idx = blockIdx.x * 256 + threadIdx.x;
    if (idx >= 1152) return;
    if (idx < 1024) {
        int which = idx >> 9;            // 0 = src, 1 = dst
        int r = idx & 511;
        int h = r >> 7, i = r & 127;
        const float* W = which ? Wdst : Wsrc;
        const float* a = attns + h * 192 + (which ? 64 : 0);
        const float* row = W + h * 8192 + i * 64;
        float s = 0.f;
#pragma unroll
        for (int o = 0; o < 64; ++o) s += row[o] * a[o];
        ws[which * 512 + h * 128 + i] = s;
    } else {
        int r = idx - 1024;
        int h = r >> 5, e = r & 31;
        const float* a = attns + h * 192 + 128;
        const float* row = Wedge + h * 2048 + e * 64;
        float s = 0.f;
#pragma unroll
        for (int o = 0; o < 64; ++o) s += row[o] * a[o];
        ws[1024 + h * 32 + e] = s;
    }
}

// ---------------- K1: s_src table ss[bb][h][n] = x[bb,n,:]·v_src[h] --------
__global__ __launch_bounds__(256) void k_ssrc(const float* __restrict__ x,
                                              const float* __restrict__ ws,
                                              float* __restrict__ ss) {
    int wave = threadIdx.x >> 6, l = threadIdx.x & 63;
    int row = blockIdx.x * 4 + wave;     // 0..8191  (= bb*32 + n)
    float2 x2 = *(const float2*)(x + (size_t)row * 128 + l * 2);
    float p[4];
#pragma unroll
    for (int h = 0; h < 4; ++h) {
        float2 v = *(const float2*)(ws + h * 128 + l * 2);
        p[h] = x2.x * v.x + x2.y * v.y;
    }
#pragma unroll
    for (int mm = 1; mm < 64; mm <<= 1) {
#pragma unroll
        for (int h = 0; h < 4; ++h) p[h] += __shfl_xor(p[h], mm, 64);
    }
    if (l == 0) {
        int bb = row >> 5, n = row & 31;
#pragma unroll
        for (int h = 0; h < 4; ++h) ss[bb * 128 + h * 32 + n] = p[h];
    }
}

// ---------------- KB: scores + softmax + adj aggregation -------------------
__global__ __launch_bounds__(256) void k_attn(const float* __restrict__ adjx,
                                              const float* __restrict__ edge,
                                              const int* __restrict__ masks,
                                              const float* __restrict__ ws,
                                              float* __restrict__ agg) {
    __shared__ float tile[32 * 128];     // adj tile [n][i]
    __shared__ float sdst[4][32];
    __shared__ float sedge[4][32];
    __shared__ float wts[4][32];

    int t = threadIdx.x;
    int bid = blockIdx.x;                // b*32 + m
    int b = bid >> 5, m = bid & 31;
    int lane32 = t & 31;

    // v_dst fragments (i = lane32*4 .. +3), constant per thread
    float4 vd[4];
#pragma unroll
    for (int h = 0; h < 4; ++h)
        vd[h] = *(const float4*)(ws + 512 + h * 128 + lane32 * 4);

    const float4* atile = (const float4*)(adjx + (size_t)bid * 4096);

    // ---- load adj tile to LDS, fuse s_dst partial dots + 32-lane reduce ----
#pragma unroll
    for (int k = 0; k < 4; ++k) {
        int f4 = k * 256 + t;            // float4 index: n = f4/32, i = (f4%32)*4
        float4 v = atile[f4];
        ((float4*)tile)[f4] = v;
        float p[4];
#pragma unroll
        for (int h = 0; h < 4; ++h)
            p[h] = v.x * vd[h].x + v.y * vd[h].y + v.z * vd[h].z + v.w * vd[h].w;
#pragma unroll
        for (int mm = 1; mm < 32; mm <<= 1) {
#pragma unroll
            for (int h = 0; h < 4; ++h) p[h] += __shfl_xor(p[h], mm, 32);
        }
        if (lane32 == 0) {
            int n = k * 8 + (t >> 5);
#pragma unroll
            for (int h = 0; h < 4; ++h) sdst[h][n] = p[h];
        }
    }

    // ---- edge tile: s_edge via 8-lane reduce ----
    {
        int e4 = t & 7;                  // e = e4*4, n = t/8
        float4 ve[4];
#pragma unroll
        for (int h = 0; h < 4; ++h)
            ve[h] = *(const float4*)(ws + 1024 + h * 32 + e4 * 4);
        float4 v = ((const float4*)(edge + (size_t)bid * 1024))[t];
        float p[4];
#pragma unroll
        for (int h = 0; h < 4; ++h)
            p[h] = v.x * ve[h].x + v.y * ve[h].y + v.z * ve[h].z + v.w * ve[h].w;
#pragma unroll
        for (int mm = 1; mm < 8; mm <<= 1) {
#pragma unroll
            for (int h = 0; h < 4; ++h) p[h] += __shfl_xor(p[h], mm, 8);
        }
        if (e4 == 0) {
            int n = t >> 3;
#pragma unroll
            for (int h = 0; h < 4; ++h) sedge[h][n] = p[h];
        }
    }
    __syncthreads();

    // ---- softmax: wave h, lanes handle n (duplicated in both halves) ----
    {
        int h = t >> 6, l = t & 63, n = l & 31;
        int bb = (b & 7) * 32 + m;       // the reference's scrambled tile+reshape
        float s = ws[1152 + bb * 128 + h * 32 + n] + sdst[h][n] + sedge[h][n];
        s = s > 0.f ? s : 0.2f * s;      // leaky relu
        if (masks[bid * 32 + n] == 0) s = NEG_INF_F;
        float mx = s;
#pragma unroll
        for (int mm = 1; mm < 32; mm <<= 1) mx = fmaxf(mx, __shfl_xor(mx, mm, 32));
        float e = __expf(s - mx);
        float sum = e;
#pragma unroll
        for (int mm = 1; mm < 32; mm <<= 1) sum += __shfl_xor(sum, mm, 32);
        if (l < 32) wts[h][n] = e / sum;
    }
    __syncthreads();

    // ---- aggregate: agg[h][i] = sum_n wts[h][n] * tile[n][i] ----
    {
        int i = t & 127, h0 = t >> 7;    // thread covers heads h0 and h0+2
        float a0 = 0.f, a1 = 0.f;
#pragma unroll
        for (int n = 0; n < 32; ++n) {
            float v = tile[n * 128 + i];
            a0 += wts[h0][n] * v;
            a1 += wts[h0 + 2][n] * v;
        }
        float* op = agg + (size_t)bid * 512;
        op[h0 * 128 + i] = a0;
        op[(h0 + 2) * 128 + i] = a1;
    }
}

// ---------------- KC: out[r][h*64+o] = x[r]·W_src[h] + agg[r,h]·W_dst[h] ---
__global__ __launch_bounds__(256) void k_out(const float* __restrict__ x,
                                             const float* __restrict__ agg,
                                             const float* __restrict__ Wsrc,
                                             const float* __restrict__ Wdst,
                                             float* __restrict__ out) {
    // stride 257 == 1 (mod 32): read ubuf[l][i] across 64 lanes -> 2 lanes/bank (free)
    __shared__ float ubuf[64][257];      // 64 rows x (x:128 | agg:128)
    int t = threadIdx.x;
    int r0 = blockIdx.x * 64;
    int h = blockIdx.y;

    // stage u rows (scalar LDS writes; rows are not 16B-aligned with stride 257)
#pragma unroll
    for (int k = 0; k < 16; ++k) {
        int f4 = k * 256 + t;            // 4096 float4s total
        int row = f4 >> 6;
        int c = (f4 & 63) * 4;
        float4 v;
        if (c < 128)
            v = *(const float4*)(x + (size_t)(r0 + row) * 128 + c);
        else
            v = *(const float4*)(agg + (size_t)(r0 + row) * 512 + h * 128 + (c - 128));
        ubuf[row][c]     = v.x;
        ubuf[row][c + 1] = v.y;
        ubuf[row][c + 2] = v.z;
        ubuf[row][c + 3] = v.w;
    }
    __syncthreads();

    int w = t >> 6, l = t & 63;          // lane = row, wave picks o-range
    int o0 = __builtin_amdgcn_readfirstlane(w * 16);
    const float* Ws = Wsrc + h * 8192 + o0;
    const float* Wd = Wdst + h * 8192 + o0;
    float acc[16];
#pragma unroll
    for (int j = 0; j < 16; ++j) acc[j] = 0.f;

    for (int i = 0; i < 128; ++i) {
        float u = ubuf[l][i];
        const float* wr = Ws + i * 64;
#pragma unroll
        for (int j = 0; j < 16; ++j) acc[j] += u * wr[j];
    }
    for (int i = 0; i < 128; ++i) {
        float u = ubuf[l][128 + i];
        const float* wr = Wd + i * 64;
#pragma unroll
        for (int j = 0; j < 16; ++j) acc[j] += u * wr[j];
    }

    float* op = out + (size_t)(r0 + l) * 256 + h * 64 + o0;
#pragma unroll
    for (int j = 0; j < 16; ++j) op[j] = acc[j];
}

extern "C" void kernel_launch(void* const* d_in, const int* in_sizes, int n_in,
                              void* d_out, int out_size, void* d_ws, size_t ws_size,
                              hipStream_t stream) {
    const float* x     = (const float*)d_in[0];
    const float* adjx  = (const float*)d_in[1];
    const int*   masks = (const int*)  d_in[2];
    const float* edge  = (const float*)d_in[3];
    const float* Wsrc  = (const float*)d_in[4];
    const float* Wdst  = (const float*)d_in[5];
    const float* Wedge = (const float*)d_in[6];
    const float* attns = (const float*)d_in[7];
    float* ws  = (float*)d_ws;
    float* ss  = ws + 1152;
    float* agg = ws + 40960;
    float* out = (float*)d_out;

    hipLaunchKernelGGL(k_vecs, dim3(5),        dim3(256), 0, stream, Wsrc, Wdst, Wedge, attns, ws);
    hipLaunchKernelGGL(k_ssrc, dim3(2048),     dim3(256), 0, stream, x, ws, ss);
    hipLaunchKernelGGL(k_attn, dim3(8192),     dim3(256), 0, stream, adjx, edge, masks, ws, agg);
    hipLaunchKernelGGL(k_out,  dim3(128, 4),   dim3(256), 0, stream, x, agg, Wsrc, Wdst, out);
}

// Round 5
// 267.890 us; speedup vs baseline: 1.0531x; 1.0531x over previous
//
#include <hip/hip_runtime.h>

#define NEG_INF_F (-9000000000000000.0f)
// B=256, N=32, IN=128, OUT=64, ED=32, H=4
// ws layout (floats):
//   [0..512)      v_src[h][i]
//   [512..1024)   v_dst[h][i]
//   [1024..1152)  v_edge[h][e]
//   [1152..33920) ss[bb][h][n]   (256*4*32)
//   [40960..)     agg[bid][h][i] (8192*4*128 floats)

// ---------------- K0: projection vectors v_src/v_dst/v_edge ----------------
__global__ __launch_bounds__(256) void k_vecs(const float* __restrict__ Wsrc,
                                              const float* __restrict__ Wdst,
                                              const float* __restrict__ Wedge,
                                              const float* __restrict__ attns,
                                              float* __restrict__ ws) {
    int idx = blockIdx.x * 256 + threadIdx.x;
    if (idx >= 1152) return;
    if (idx < 1024) {
        int which = idx >> 9;            // 0 = src, 1 = dst
        int r = idx & 511;
        int h = r >> 7, i = r & 127;
        const float* W = which ? Wdst : Wsrc;
        const float* a = attns + h * 192 + (which ? 64 : 0);
        const float* row = W + h * 8192 + i * 64;
        float s = 0.f;
#pragma unroll
        for (int o = 0; o < 64; ++o) s += row[o] * a[o];
        ws[which * 512 + h * 128 + i] = s;
    } else {
        int r = idx - 1024;
        int h = r >> 5, e = r & 31;
        const float* a = attns + h * 192 + 128;
        const float* row = Wedge + h * 2048 + e * 64;
        float s = 0.f;
#pragma unroll
        for (int o = 0; o < 64; ++o) s += row[o] * a[o];
        ws[1024 + h * 32 + e] = s;
    }
}

// ---------------- K1: s_src table ss[bb][h][n] = x[bb,n,:]·v_src[h] --------
__global__ __launch_bounds__(256) void k_ssrc(const float* __restrict__ x,
                                              const float* __restrict__ ws,
                                              float* __restrict__ ss) {
    int wave = threadIdx.x >> 6, l = threadIdx.x & 63;
    int row = blockIdx.x * 4 + wave;     // 0..8191  (= bb*32 + n)
    float2 x2 = *(const float2*)(x + (size_t)row * 128 + l * 2);
    float p[4];
#pragma unroll
    for (int h = 0; h < 4; ++h) {
        float2 v = *(const float2*)(ws + h * 128 + l * 2);
        p[h] = x2.x * v.x + x2.y * v.y;
    }
#pragma unroll
    for (int mm = 1; mm < 64; mm <<= 1) {
#pragma unroll
        for (int h = 0; h < 4; ++h) p[h] += __shfl_xor(p[h], mm, 64);
    }
    if (l == 0) {
        int bb = row >> 5, n = row & 31;
#pragma unroll
        for (int h = 0; h < 4; ++h) ss[bb * 128 + h * 32 + n] = p[h];
    }
}

// ---------------- KB: scores + softmax + adj aggregation -------------------
// LDS-pipe budget cut ~200 -> ~65 wave-instrs/thread:
//   s_dst reduce: head-interleaved butterfly (6 shfl/k-iter, was 20)
//   edge reduce: 4 shfl (was 12)
//   aggregate: b128 tile + b128 wts reads on 128 threads (was 96 scalar/thread)
__global__ __launch_bounds__(256) void k_attn(const float* __restrict__ adjx,
                                              const float* __restrict__ edge,
                                              const int* __restrict__ masks,
                                              const float* __restrict__ ws,
                                              float* __restrict__ agg) {
    __shared__ float tile[32 * 128];     // adj tile [n][i] (float4-granular)
    __shared__ float sdst[4][32];
    __shared__ float sedge[4][32];
    __shared__ float wts[4][32];

    int t = threadIdx.x;
    int bid = blockIdx.x;                // b*32 + m
    int b = bid >> 5, m = bid & 31;
    int l32 = t & 31;

    // ---- issue ALL independent global loads up front (latency hiding) ----
    int bb = (b & 7) * 32 + m;           // reference's scrambled tile+reshape
    float ssv = ws[1152 + bb * 128 + (t >> 6) * 32 + l32]; // s_src for (h=t>>6, n=l32)
    int   mk  = masks[bid * 32 + l32];

    float4 vd[4];
#pragma unroll
    for (int h = 0; h < 4; ++h)
        vd[h] = *(const float4*)(ws + 512 + h * 128 + l32 * 4);

    int e4 = t & 7;
    float4 ve[4];
#pragma unroll
    for (int h = 0; h < 4; ++h)
        ve[h] = *(const float4*)(ws + 1024 + h * 32 + e4 * 4);
    float4 ev = ((const float4*)(edge + (size_t)bid * 1024))[t];

    const float4* atile = (const float4*)(adjx + (size_t)bid * 4096);
    float4 av[4];
#pragma unroll
    for (int k = 0; k < 4; ++k) av[k] = atile[k * 256 + t];

    // ---- stage tile + fused s_dst (per k: n = k*8 + t/32, i4 = l32) ----
#pragma unroll
    for (int k = 0; k < 4; ++k) {
        ((float4*)tile)[k * 256 + t] = av[k];
        float p0 = av[k].x * vd[0].x + av[k].y * vd[0].y + av[k].z * vd[0].z + av[k].w * vd[0].w;
        float p1 = av[k].x * vd[1].x + av[k].y * vd[1].y + av[k].z * vd[1].z + av[k].w * vd[1].w;
        float p2 = av[k].x * vd[2].x + av[k].y * vd[2].y + av[k].z * vd[2].z + av[k].w * vd[2].w;
        float p3 = av[k].x * vd[3].x + av[k].y * vd[3].y + av[k].z * vd[3].z + av[k].w * vd[3].w;
        // head-interleaved butterfly over the 32-lane group
        float s0 = (l32 & 1) ? p0 : p1;          // send what partner keeps
        float s1 = (l32 & 1) ? p2 : p3;
        float r0 = __shfl_xor(s0, 1);
        float r1 = __shfl_xor(s1, 1);
        float a  = ((l32 & 1) ? p1 : p0) + r0;   // head (l&1), sum of 2 lanes
        float bv = ((l32 & 1) ? p3 : p2) + r1;   // head 2+(l&1)
        float s2 = (l32 & 2) ? a : bv;
        float r2 = __shfl_xor(s2, 2);
        float c  = ((l32 & 2) ? bv : a) + r2;    // head (l&3), sum of 4 lanes
        c += __shfl_xor(c, 4);
        c += __shfl_xor(c, 8);
        c += __shfl_xor(c, 16);                  // sum of 32 lanes
        if (l32 < 4) sdst[l32][k * 8 + (t >> 5)] = c;
    }

    // ---- edge scores: n = t/8, e-range = (t&7)*4; butterfly over 8 lanes ----
    {
        float p0 = ev.x * ve[0].x + ev.y * ve[0].y + ev.z * ve[0].z + ev.w * ve[0].w;
        float p1 = ev.x * ve[1].x + ev.y * ve[1].y + ev.z * ve[1].z + ev.w * ve[1].w;
        float p2 = ev.x * ve[2].x + ev.y * ve[2].y + ev.z * ve[2].z + ev.w * ve[2].w;
        float p3 = ev.x * ve[3].x + ev.y * ve[3].y + ev.z * ve[3].z + ev.w * ve[3].w;
        float s0 = (t & 1) ? p0 : p1;
        float s1 = (t & 1) ? p2 : p3;
        float r0 = __shfl_xor(s0, 1);
        float r1 = __shfl_xor(s1, 1);
        float a  = ((t & 1) ? p1 : p0) + r0;
        float bv = ((t & 1) ? p3 : p2) + r1;
        float s2 = (t & 2) ? a : bv;
        float r2 = __shfl_xor(s2, 2);
        float c  = ((t & 2) ? bv : a) + r2;
        c += __shfl_xor(c, 4);                   // sum over the 8-lane group
        if ((t & 7) < 4) sedge[t & 3][t >> 3] = c;
    }
    __syncthreads();

    // ---- softmax: wave h = t>>6, n = l32 (both 32-halves duplicate work) ----
    {
        int h = t >> 6;
        float s = ssv + sdst[h][l32] + sedge[h][l32];
        s = s > 0.f ? s : 0.2f * s;              // leaky relu
        if (mk == 0) s = NEG_INF_F;
        float mx = s;
#pragma unroll
        for (int mm = 1; mm < 32; mm <<= 1) mx = fmaxf(mx, __shfl_xor(mx, mm));
        float e = __expf(s - mx);
        float sum = e;
#pragma unroll
        for (int mm = 1; mm < 32; mm <<= 1) sum += __shfl_xor(sum, mm);
        if ((t & 63) < 32) wts[h][l32] = e / sum;
    }
    __syncthreads();

    // ---- aggregate: threads t<128, (h = t>>5, i4 = t&31) own a float4 of agg ----
    if (t < 128) {
        int h = t >> 5, i4 = t & 31;
        float4 acc = {0.f, 0.f, 0.f, 0.f};
#pragma unroll
        for (int n4 = 0; n4 < 8; ++n4) {
            float4 w4 = *(const float4*)&wts[h][n4 * 4];
            const float4* tp = (const float4*)tile + n4 * 128 + i4;   // tile4[n4*4][i4]
            float4 v0 = tp[0], v1 = tp[32], v2 = tp[64], v3 = tp[96];
            acc.x += w4.x * v0.x + w4.y * v1.x + w4.z * v2.x + w4.w * v3.x;
            acc.y += w4.x * v0.y + w4.y * v1.y + w4.z * v2.y + w4.w * v3.y;
            acc.z += w4.x * v0.z + w4.y * v1.z + w4.z * v2.z + w4.w * v3.z;
            acc.w += w4.x * v0.w + w4.y * v1.w + w4.z * v2.w + w4.w * v3.w;
        }
        ((float4*)(agg + (size_t)bid * 512))[h * 32 + i4] = acc;      // coalesced b128
    }
}

// ---------------- KC: out[r][h*64+o] = x[r]·W_src[h] + agg[r,h]·W_dst[h] ---
__global__ __launch_bounds__(256) void k_out(const float* __restrict__ x,
                                             const float* __restrict__ agg,
                                             const float* __restrict__ Wsrc,
                                             const float* __restrict__ Wdst,
                                             float* __restrict__ out) {
    // stride 257 == 1 (mod 32): read ubuf[l][i] across 64 lanes -> 2 lanes/bank (free)
    __shared__ float ubuf[64][257];      // 64 rows x (x:128 | agg:128)
    int t = threadIdx.x;
    int r0 = blockIdx.x * 64;
    int h = blockIdx.y;

#pragma unroll
    for (int k = 0; k < 16; ++k) {
        int f4 = k * 256 + t;            // 4096 float4s total
        int row = f4 >> 6;
        int c = (f4 & 63) * 4;
        float4 v;
        if (c < 128)
            v = *(const float4*)(x + (size_t)(r0 + row) * 128 + c);
        else
            v = *(const float4*)(agg + (size_t)(r0 + row) * 512 + h * 128 + (c - 128));
        ubuf[row][c]     = v.x;
        ubuf[row][c + 1] = v.y;
        ubuf[row][c + 2] = v.z;
        ubuf[row][c + 3] = v.w;
    }
    __syncthreads();

    int w = t >> 6, l = t & 63;          // lane = row, wave picks o-range
    int o0 = __builtin_amdgcn_readfirstlane(w * 16);
    const float* Ws = Wsrc + h * 8192 + o0;
    const float* Wd = Wdst + h * 8192 + o0;
    float acc[16];
#pragma unroll
    for (int j = 0; j < 16; ++j) acc[j] = 0.f;

#pragma unroll 4
    for (int i = 0; i < 128; ++i) {
        float u = ubuf[l][i];
        const float* wr = Ws + i * 64;
#pragma unroll
        for (int j = 0; j < 16; ++j) acc[j] += u * wr[j];
    }
#pragma unroll 4
    for (int i = 0; i < 128; ++i) {
        float u = ubuf[l][128 + i];
        const float* wr = Wd + i * 64;
#pragma unroll
        for (int j = 0; j < 16; ++j) acc[j] += u * wr[j];
    }

    float* op = out + (size_t)(r0 + l) * 256 + h * 64 + o0;
#pragma unroll
    for (int j = 0; j < 16; ++j) op[j] = acc[j];
}

extern "C" void kernel_launch(void* const* d_in, const int* in_sizes, int n_in,
                              void* d_out, int out_size, void* d_ws, size_t ws_size,
                              hipStream_t stream) {
    const float* x     = (const float*)d_in[0];
    const float* adjx  = (const float*)d_in[1];
    const int*   masks = (const int*)  d_in[2];
    const float* edge  = (const float*)d_in[3];
    const float* Wsrc  = (const float*)d_in[4];
    const float* Wdst  = (const float*)d_in[5];
    const float* Wedge = (const float*)d_in[6];
    const float* attns = (const float*)d_in[7];
    float* ws  = (float*)d_ws;
    float* ss  = ws + 1152;
    float* agg = ws + 40960;
    float* out = (float*)d_out;

    hipLaunchKernelGGL(k_vecs, dim3(5),        dim3(256), 0, stream, Wsrc, Wdst, Wedge, attns, ws);
    hipLaunchKernelGGL(k_ssrc, dim3(2048),     dim3(256), 0, stream, x, ws, ss);
    hipLaunchKernelGGL(k_attn, dim3(8192),     dim3(256), 0, stream, adjx, edge, masks, ws, agg);
    hipLaunchKernelGGL(k_out,  dim3(128, 4),   dim3(256), 0, stream, x, agg, Wsrc, Wdst, out);
}